// Round 5
// baseline (855.625 us; speedup 1.0000x reference)
//
#include <hip/hip_runtime.h>
#include <math.h>

// Router: logits = x[32768,4096] @ w[64,4096]^T, softmax->top2->renorm.
//
// MFMA version: fp32 inputs split into bf16 hi+lo (x=xh+xl, w=wh+wl, truncation),
// logits = xh*wh + xl*wh + xh*wl via mfma_f32_16x16x32_bf16 (error ~1e-5 << DELTA).
//
// v5: fix the in-order-vmcnt retirement hazard.
//   vmcnt retires loads IN ISSUE ORDER. v4 issued [A-stage(i+1) HBM] then
//   [B-loads L2] inside compute; every compiler wait on a B-load forced
//   retirement of the younger-…older HBM batch -> pipeline depth 0, each
//   iteration ate a full loaded-HBM round trip (351us, all pipes idle).
//   v5 per iteration: (1) issue B(i) frag loads to REGISTERS (older),
//   (2) issue A(i+1) global_load_lds (younger), (3) vmcnt(20) retires A(i)
//   only, (4) compute: A from LDS (lgkmcnt), B from regs — B waits never
//   drain A(i+1). KT=64 so the B tile fits in 64 VGPRs.
//   Wave-private LDS (no barriers in K loop), pre-swizzled global source +
//   swizzled ds_read_b128, per-wave K-phase stagger kept.
//
// d_out layout (float32):
//   [0      , 65536 ) : indices [8,4096,2] as float
//   [65536  , 131072) : weights [8,4096,2]
//   [131072 , end   ) : logits  [8,4096,64]
//
// d_ws layout:
//   [0, 1M): w split bf16: hi plane [64][4096] ushort, then lo plane

#define DELTA  1e-3f
#define LS     68            // logits LDS stride (floats)
#define WPLANE 262144        // elems per w bf16 plane (64*4096)
#define NT     64            // K tiles (4096 / 64)

typedef __bf16 bf16x8 __attribute__((ext_vector_type(8)));
typedef float  f32x4  __attribute__((ext_vector_type(4)));

#define MFMA(a, b, c) __builtin_amdgcn_mfma_f32_16x16x32_bf16(a, b, c, 0, 0, 0)

#define GLL16(gp, lp) __builtin_amdgcn_global_load_lds(                          \
    (const __attribute__((address_space(1))) unsigned*)(gp),                     \
    (__attribute__((address_space(3))) unsigned*)(lp), 16, 0, 0)

__device__ __forceinline__ void split1(float x, unsigned short& h, unsigned short& l)
{
    const unsigned xb = __float_as_uint(x);
    const unsigned hb = xb & 0xffff0000u;
    h = (unsigned short)(hb >> 16);
    const float fl = x - __uint_as_float(hb);      // exact in fp32
    l = (unsigned short)(__float_as_uint(fl) >> 16);
}

// 8 fp32 -> bf16 hi plane + bf16 lo plane (truncation; identical to split1)
__device__ __forceinline__ void split8(const f32x4 v0, const f32x4 v1,
                                       bf16x8& ah, bf16x8& al)
{
    union U { bf16x8 v; unsigned u[4]; };
    U h, l;
    const unsigned a0 = __float_as_uint(v0[0]), a1 = __float_as_uint(v0[1]);
    const unsigned a2 = __float_as_uint(v0[2]), a3 = __float_as_uint(v0[3]);
    const unsigned b0 = __float_as_uint(v1[0]), b1 = __float_as_uint(v1[1]);
    const unsigned b2 = __float_as_uint(v1[2]), b3 = __float_as_uint(v1[3]);
    h.u[0] = (a0 >> 16) | (a1 & 0xffff0000u);
    h.u[1] = (a2 >> 16) | (a3 & 0xffff0000u);
    h.u[2] = (b0 >> 16) | (b1 & 0xffff0000u);
    h.u[3] = (b2 >> 16) | (b3 & 0xffff0000u);
    const float f0 = v0[0] - __uint_as_float(a0 & 0xffff0000u);
    const float f1 = v0[1] - __uint_as_float(a1 & 0xffff0000u);
    const float f2 = v0[2] - __uint_as_float(a2 & 0xffff0000u);
    const float f3 = v0[3] - __uint_as_float(a3 & 0xffff0000u);
    const float f4 = v1[0] - __uint_as_float(b0 & 0xffff0000u);
    const float f5 = v1[1] - __uint_as_float(b1 & 0xffff0000u);
    const float f6 = v1[2] - __uint_as_float(b2 & 0xffff0000u);
    const float f7 = v1[3] - __uint_as_float(b3 & 0xffff0000u);
    l.u[0] = (__float_as_uint(f0) >> 16) | (__float_as_uint(f1) & 0xffff0000u);
    l.u[1] = (__float_as_uint(f2) >> 16) | (__float_as_uint(f3) & 0xffff0000u);
    l.u[2] = (__float_as_uint(f4) >> 16) | (__float_as_uint(f5) & 0xffff0000u);
    l.u[3] = (__float_as_uint(f6) >> 16) | (__float_as_uint(f7) & 0xffff0000u);
    ah = h.v;
    al = l.v;
}

// ---- w pre-split: fp32 [64][4096] -> bf16 hi/lo planes in workspace ----
__global__ __launch_bounds__(256)
void router_wconv(const float* __restrict__ w, unsigned short* __restrict__ wsp)
{
    const int i = (blockIdx.x * 256 + threadIdx.x) * 4;   // 256 blocks cover 262144
    const float4 v = *(const float4*)(w + i);
    ushort4 h4, l4;
    split1(v.x, h4.x, l4.x);
    split1(v.y, h4.y, l4.y);
    split1(v.z, h4.z, l4.z);
    split1(v.w, h4.w, l4.w);
    *(ushort4*)(wsp + i)          = h4;
    *(ushort4*)(wsp + WPLANE + i) = l4;
}

// ---- fused: MFMA GEMM + logits + top-2 + inline fp64 repair ----
// BM=64 rows/block, 256 threads (4 waves x 16 rows), KT=64, grid 512.
__global__ __launch_bounds__(256, 2)
void router_pass1(const float* __restrict__ x,
                  const unsigned short* __restrict__ wsp,
                  const float* __restrict__ w,
                  float* __restrict__ out)
{
    // two fp32 A-tile buffers [64 rows][256B] = 2x16KB; epilogue overlays logits
    __shared__ __align__(16) char smem[32768];

    const int tid  = threadIdx.x;
    const int lane = tid & 63;
    const int wv   = tid >> 6;                  // 0..3
    const int row0 = blockIdx.x * 64;

    const int fr = lane & 15;                   // frag row (A) / col (B,D)
    const int fq = lane >> 4;                   // 0..3; k offset = fq*8

    // per-wave K-phase stagger over the 64 column windows
    const int t0 = ((blockIdx.x << 2) + wv) & 63;

    f32x4 acc[4];
#pragma unroll
    for (int ct = 0; ct < 4; ++ct) {
        acc[ct][0] = 0.f; acc[ct][1] = 0.f; acc[ct][2] = 0.f; acc[ct][3] = 0.f;
    }

    // ---- A staging addresses (wave-private: wave wv stages rows wv*16..+15) ----
    // GLL16 j covers rows wv*16 + j*4 .. +3 (lane l -> row +(l>>4), byte (l&15)*16)
    const char* gsrc[4];
    char*       lbas[4];
#pragma unroll
    for (int j = 0; j < 4; ++j) {
        const int row = wv * 16 + j * 4 + (lane >> 4);
        const unsigned swz = ((unsigned)((lane & 15) * 16)) ^ ((unsigned)((row & 7) << 4));
        gsrc[j] = (const char*)x + (size_t)(row0 + row) * 16384 + swz;   // pre-swizzled
        lbas[j] = smem + (wv * 16 + j * 4) * 256;                        // linear dest
    }

    // B fragment global bases: lane reads w[e=ct*16+fr][k0+fq*8 .. +7] (16B, L2)
    const unsigned short* wb[4];
#pragma unroll
    for (int ct = 0; ct < 4; ++ct)
        wb[ct] = wsp + (size_t)(ct * 16 + fr) * 4096 + fq * 8;

    // A fragment read base (swizzled ds_read_b128)
    const int arow = wv * 16 + fr;
    const unsigned aswz = (unsigned)((arow & 7) << 4);
    const char* abase = smem + arow * 256;

    // prologue: issue tile t0 into buf 0
#pragma unroll
    for (int j = 0; j < 4; ++j) GLL16(gsrc[j] + (size_t)t0 * 256, lbas[j]);

#pragma unroll 1
    for (int i = 0; i < NT; ++i) {
        const int t = (t0 + i) & 63;

        // (1) B-fragment loads for tile t -> registers (L2 hits, OLDER than A(i+1))
        bf16x8 bh[2][4], bl[2][4];
#pragma unroll
        for (int ks = 0; ks < 2; ++ks) {
#pragma unroll
            for (int ct = 0; ct < 4; ++ct) {
                const unsigned short* p = wb[ct] + t * 64 + ks * 32;
                bh[ks][ct] = *(const bf16x8*)(p);
                bl[ks][ct] = *(const bf16x8*)(p + WPLANE);
            }
        }
        asm volatile("" ::: "memory");          // pin: B-loads issued before GLL16s
        __builtin_amdgcn_sched_barrier(0);

        // (2) issue next A tile (YOUNGER than B(i): B waits won't drain it)
        if (i + 1 < NT) {
            const int    tn = (t0 + i + 1) & 63;
            const size_t go = (size_t)tn * 256;
            const int    bo = ((i + 1) & 1) * 16384;
#pragma unroll
            for (int j = 0; j < 4; ++j) GLL16(gsrc[j] + go, lbas[j] + bo);
            // (3) retire exactly A(i): outstanding = B(i):16 + A(i+1):4
            asm volatile("s_waitcnt vmcnt(20)" ::: "memory");
        } else {
            asm volatile("s_waitcnt vmcnt(16)" ::: "memory");
        }
        __builtin_amdgcn_sched_barrier(0);

        // (4) compute tile i: A from LDS (lgkmcnt), B from registers
        const char* bufc = abase + (i & 1) * 16384;
#pragma unroll
        for (int ks = 0; ks < 2; ++ks) {
            const unsigned i0 = (unsigned)(ks * 128 + fq * 32);
            const f32x4 v0 = *(const f32x4*)(bufc + ( i0        ^ aswz));
            const f32x4 v1 = *(const f32x4*)(bufc + ((i0 + 16u) ^ aswz));
            bf16x8 ah, al;
            split8(v0, v1, ah, al);
#pragma unroll
            for (int ct = 0; ct < 4; ++ct) {
                acc[ct] = MFMA(ah, bh[ks][ct], acc[ct]);
                acc[ct] = MFMA(al, bh[ks][ct], acc[ct]);
                acc[ct] = MFMA(ah, bl[ks][ct], acc[ct]);
            }
        }
    }

    // ---- epilogue: logits via LDS (overlay A buffers), top-2, flags ----
    __syncthreads();                            // all waves done with A buffers
    float* l_lds   = (float*)smem;              // [64][LS] = 17408 B
    int*   flg_lds = (int*)(smem + 24576);      // 64 ints (disjoint from l_lds)

    // D layout: col = lane&15, row = (lane>>4)*4 + reg  [m89-verified]
#pragma unroll
    for (int ct = 0; ct < 4; ++ct) {
#pragma unroll
        for (int i = 0; i < 4; ++i) {
            l_lds[(wv * 16 + fq * 4 + i) * LS + ct * 16 + fr] = acc[ct][i];
        }
    }
    __syncthreads();

    {
        float* lg = out + 131072 + (size_t)row0 * 64;
#pragma unroll
        for (int j = 0; j < 4; ++j) {
            const int f = j * 1024 + tid * 4;
            const int r = f >> 6, e = f & 63;
            const float4 v = *(const float4*)(&l_lds[r * LS + e]);
            *(float4*)(lg + f) = v;
        }
    }

    if (tid < 64) {
        const int r = tid;
        float b1 = -3.4e38f, b2 = -3.4e38f, b3 = -3.4e38f;
        int i1 = 0, i2 = 0;
        for (int eq = 0; eq < 16; ++eq) {
            const float4 v4 = *(const float4*)(&l_lds[r * LS + eq * 4]);
            const float vv[4] = {v4.x, v4.y, v4.z, v4.w};
#pragma unroll
            for (int j = 0; j < 4; ++j) {
                const float v = vv[j];
                const int   e = eq * 4 + j;
                if (v > b1)      { b3 = b2; b2 = b1; i2 = i1; b1 = v; i1 = e; }
                else if (v > b2) { b3 = b2; b2 = v; i2 = e; }
                else if (v > b3) { b3 = v; }
            }
        }
        const int amb = ((b1 - b2 < DELTA) || (b2 - b3 < DELTA)) ? 1 : 0;
        flg_lds[r] = amb;
        if (!amb) {                 // unambiguous rows finalized here
            const float g   = __expf(b2 - b1);
            const float inv = 1.0f / (1.0f + g);
            const size_t o  = (size_t)(row0 + r) * 2;
            out[o]     = (float)i1;
            out[o + 1] = (float)i2;
            out[65536 + o]     = inv;
            out[65536 + o + 1] = g * inv;
        }
    }
    __syncthreads();

    // ---- inline fp64 repair: wave wv owns rows wv*16 .. wv*16+15 ----
    for (int i = 0; i < 16; ++i) {
        const int r = wv * 16 + i;
        if (!flg_lds[r]) continue;              // wave-uniform (LDS broadcast)
        const int row = row0 + r;

        float wval = l_lds[r * LS + lane];      // lane = expert, stride-4B: no conflicts

        int ec[4];
#pragma unroll
        for (int m = 0; m < 4; ++m) {
            float v = wval;
            int   id = lane;
            // argmax with lowest-index tie-break
            for (int off = 32; off; off >>= 1) {
                const float ov = __shfl_xor(v, off);
                const int   oi = __shfl_xor(id, off);
                if (ov > v || (ov == v && oi < id)) { v = ov; id = oi; }
            }
            ec[m] = id;                         // uniform across lanes
            if (lane == id) wval = -3.4e38f;
        }

        double s0 = 0.0, s1 = 0.0, s2 = 0.0, s3 = 0.0;
        const float* xr = x + (size_t)row * 4096;
        const float* w0 = w + (size_t)ec[0] * 4096;
        const float* w1 = w + (size_t)ec[1] * 4096;
        const float* w2 = w + (size_t)ec[2] * 4096;
        const float* w3 = w + (size_t)ec[3] * 4096;
        for (int k = lane; k < 4096; k += 64) {
            const double xd = (double)xr[k];
            s0 += xd * (double)w0[k];
            s1 += xd * (double)w1[k];
            s2 += xd * (double)w2[k];
            s3 += xd * (double)w3[k];
        }
        for (int off = 32; off; off >>= 1) {
            s0 += __shfl_xor(s0, off);
            s1 += __shfl_xor(s1, off);
            s2 += __shfl_xor(s2, off);
            s3 += __shfl_xor(s3, off);
        }

        if (lane == 0) {
            double v4[4] = { s0, s1, s2, s3 };
            int    id[4] = { ec[0], ec[1], ec[2], ec[3] };
#pragma unroll
            for (int a = 0; a < 3; ++a)
#pragma unroll
                for (int b = a + 1; b < 4; ++b)
                    if (v4[b] > v4[a] || (v4[b] == v4[a] && id[b] < id[a])) {
                        double tv = v4[a]; v4[a] = v4[b]; v4[b] = tv;
                        int    ti = id[a]; id[a] = id[b]; id[b] = ti;
                    }
            const double g   = exp(v4[1] - v4[0]);
            const double inv = 1.0 / (1.0 + g);
            const size_t o   = (size_t)row * 2;
            out[o]     = (float)id[0];
            out[o + 1] = (float)id[1];
            out[65536 + o]     = (float)inv;
            out[65536 + o + 1] = (float)(g * inv);
        }
    }
}

extern "C" void kernel_launch(void* const* d_in, const int* in_sizes, int n_in,
                              void* d_out, int out_size, void* d_ws, size_t ws_size,
                              hipStream_t stream) {
    const float* x = (const float*)d_in[0];   // [8,4096,4096]
    const float* w = (const float*)d_in[1];   // [64,4096]
    float* out = (float*)d_out;
    unsigned short* wsp = (unsigned short*)d_ws;   // 1 MB: w bf16 hi+lo planes

    hipLaunchKernelGGL(router_wconv, dim3(256), dim3(256), 0, stream, w, wsp);
    hipLaunchKernelGGL(router_pass1, dim3(512), dim3(256), 0, stream, x, wsp, w, out);
}